// Round 1
// baseline (4512.896 us; speedup 1.0000x reference)
//
#include <hip/hip_runtime.h>

#define V 16000
#define E 256
#define H 512
#define BB 8      // batch
#define KBM 5     // beam width
#define T 12      // lenseq
#define R 40      // KBM*BB rows
#define G3 1536   // 3*H

// ---------------- init: h_cur = broadcast(hidden), x = SOS ----------------
__global__ __launch_bounds__(256) void k0_init(const float* __restrict__ hidden,
                                               float* __restrict__ h_cur,
                                               int* __restrict__ x_cur) {
    int idx = blockIdx.x * 256 + threadIdx.x;   // R*H = 20480
    if (idx < R * H) {
        int r = idx >> 9;          // /512
        int j = idx & (H - 1);
        h_cur[idx] = hidden[(r & 7) * H + j];   // b = r % 8
        if (j == 0) x_cur[r] = 1;               // SOS
    }
}

// ---------------- GRU input/hidden GEMMs: gi = emb@w_ih^T, gh = h@w_hh^T ----
// grid 960 x 128.  blocks [0,480): gh (K=512). blocks [480,960): gi (K=256).
// per block: 32 j x 4 r (one dot per thread).
__global__ __launch_bounds__(128) void k1_gemm(const float* __restrict__ emb_tab,
                                               const float* __restrict__ w_ih,
                                               const float* __restrict__ w_hh,
                                               const int* __restrict__ x_cur,
                                               const float* __restrict__ h_cur,
                                               float* __restrict__ gi_buf,
                                               float* __restrict__ gh_buf) {
    int bid = blockIdx.x;
    bool is_gh = bid < 480;
    int lb = is_gh ? bid : bid - 480;
    int jt = lb / 10, rt = lb % 10;
    int j = jt * 32 + (threadIdx.x >> 2);
    int r = rt * 4 + (threadIdx.x & 3);

    if (is_gh) {
        const float* w = w_hh + j * H;
        const float* hv = h_cur + r * H;
        float a0 = 0.f, a1 = 0.f;
        for (int k = 0; k < H; k += 4) {
            float4 a = *(const float4*)(w + k);
            float4 b = *(const float4*)(hv + k);
            a0 += a.x * b.x + a.y * b.y;
            a1 += a.z * b.z + a.w * b.w;
        }
        gh_buf[j * R + r] = a0 + a1;
    } else {
        const float* w = w_ih + j * E;
        const float* ev = emb_tab + (size_t)x_cur[r] * E;
        float a0 = 0.f, a1 = 0.f;
        for (int k = 0; k < E; k += 4) {
            float4 a = *(const float4*)(w + k);
            float4 b = *(const float4*)(ev + k);
            a0 += a.x * b.x + a.y * b.y;
            a1 += a.z * b.z + a.w * b.w;
        }
        gi_buf[j * R + r] = a0 + a1;
    }
}

// ---------------- gates + blend:  h_next = done ? h : GRU(h) ---------------
__global__ __launch_bounds__(256) void k1b_gate(const float* __restrict__ gi_buf,
                                                const float* __restrict__ gh_buf,
                                                const float* __restrict__ b_ih,
                                                const float* __restrict__ b_hh,
                                                const int* __restrict__ x_cur,
                                                const float* __restrict__ h_cur,
                                                float* __restrict__ h_next) {
    int idx = blockIdx.x * 256 + threadIdx.x;   // R*H
    if (idx >= R * H) return;
    int r = idx >> 9;
    int j = idx & (H - 1);
    int x = x_cur[r];
    bool done = (x == 2) || (x == 0);           // EOS | PAD
    float ir = gi_buf[j * R + r]            + b_ih[j];
    float iz = gi_buf[(H + j) * R + r]      + b_ih[H + j];
    float inn = gi_buf[(2 * H + j) * R + r] + b_ih[2 * H + j];
    float hr = gh_buf[j * R + r]            + b_hh[j];
    float hz = gh_buf[(H + j) * R + r]      + b_hh[H + j];
    float hn = gh_buf[(2 * H + j) * R + r]  + b_hh[2 * H + j];
    float rg = 1.f / (1.f + __expf(-(ir + hr)));
    float zg = 1.f / (1.f + __expf(-(iz + hz)));
    float ng = tanhf(inn + rg * hn);
    float ho = h_cur[idx];
    float hv = (1.f - zg) * ng + zg * ho;
    h_next[idx] = done ? ho : hv;
}

// ---------------- logits = h_next @ w_out^T + b_out ------------------------
// grid 1000 x 128: 16 vocab cols x 8 row-groups per block; 5 rows per thread.
__global__ __launch_bounds__(128) void k2_logits(const float* __restrict__ w_out,
                                                 const float* __restrict__ b_out,
                                                 const float* __restrict__ h_next,
                                                 float* __restrict__ logits) {
    int v = blockIdx.x * 16 + (threadIdx.x >> 3);
    int rg = threadIdx.x & 7;                   // rows rg*5 .. rg*5+4
    const float* w = w_out + (size_t)v * H;
    float acc[5] = {0.f, 0.f, 0.f, 0.f, 0.f};
    for (int k = 0; k < H; k += 16) {
        float4 w4[4];
#pragma unroll
        for (int q = 0; q < 4; q++) w4[q] = *(const float4*)(w + k + 4 * q);
#pragma unroll
        for (int i = 0; i < 5; i++) {
            const float* hv = h_next + (rg * 5 + i) * H + k;
#pragma unroll
            for (int q = 0; q < 4; q++) {
                float4 h4 = *(const float4*)(hv + 4 * q);
                acc[i] += w4[q].x * h4.x + w4[q].y * h4.y + w4[q].z * h4.z + w4[q].w * h4.w;
            }
        }
    }
    float bo = b_out[v];
#pragma unroll
    for (int i = 0; i < 5; i++) logits[(rg * 5 + i) * V + v] = acc[i] + bo;
}

// ---- softmax stats + pred write + top-5 select + beam gather (1 blk/batch) -
__global__ __launch_bounds__(256) void k5_select(const float* __restrict__ logits,
                                                 float* __restrict__ preds_t,
                                                 const float* __restrict__ h_next,
                                                 float* __restrict__ h_cur,
                                                 int* __restrict__ x_cur,
                                                 int* __restrict__ P_t) {
    int b = blockIdx.x;
    int tid = threadIdx.x;
    __shared__ float red[256];
    __shared__ float s_rmax[KBM], s_rinv[KBM];
    __shared__ float tv[256 * KBM];
    __shared__ int   ti[256 * KBM];
    __shared__ int   s_beam[KBM];

    // phase A1: row maxima
    float m[KBM];
#pragma unroll
    for (int kk = 0; kk < KBM; kk++) m[kk] = -3.4e38f;
    for (int v = tid; v < V; v += 256)
#pragma unroll
        for (int kk = 0; kk < KBM; kk++)
            m[kk] = fmaxf(m[kk], logits[(kk * BB + b) * V + v]);
#pragma unroll
    for (int kk = 0; kk < KBM; kk++) {
        red[tid] = m[kk];
        __syncthreads();
        for (int s = 128; s > 0; s >>= 1) {
            if (tid < s) red[tid] = fmaxf(red[tid], red[tid + s]);
            __syncthreads();
        }
        if (tid == 0) s_rmax[kk] = red[0];
        __syncthreads();
    }
    // phase A2: sum of exp
    float sm[KBM];
#pragma unroll
    for (int kk = 0; kk < KBM; kk++) sm[kk] = 0.f;
    for (int v = tid; v < V; v += 256)
#pragma unroll
        for (int kk = 0; kk < KBM; kk++)
            sm[kk] += __expf(logits[(kk * BB + b) * V + v] - s_rmax[kk]);
#pragma unroll
    for (int kk = 0; kk < KBM; kk++) {
        red[tid] = sm[kk];
        __syncthreads();
        for (int s = 128; s > 0; s >>= 1) {
            if (tid < s) red[tid] += red[tid + s];
            __syncthreads();
        }
        if (tid == 0) s_rinv[kk] = red[0];
        __syncthreads();
    }

    // phase B: pred write + per-thread top5  (tie-break: val desc, flat idx asc)
    bool dn[KBM];
#pragma unroll
    for (int kk = 0; kk < KBM; kk++) {
        int xk = x_cur[kk * BB + b];
        dn[kk] = (xk == 0) || (xk == 2);
    }
    float val5[KBM];
    int   idx5[KBM];
#pragma unroll
    for (int q = 0; q < KBM; q++) { val5[q] = -1.f; idx5[q] = 0x7fffffff; }
    for (int v = tid; v < V; v += 256) {
#pragma unroll
        for (int kk = 0; kk < KBM; kk++) {
            float l = logits[(kk * BB + b) * V + v];
            float p;
            if (dn[kk]) p = (v == 0) ? 1.f : 0.f;
            else        p = __expf(l - s_rmax[kk]) / s_rinv[kk];
            preds_t[(kk * BB + b) * V + v] = p;
            int fi = kk * V + v;
            if (p > val5[4] || (p == val5[4] && fi < idx5[4])) {
                int pos = 4;
                while (pos > 0 && (p > val5[pos - 1] ||
                       (p == val5[pos - 1] && fi < idx5[pos - 1]))) {
                    val5[pos] = val5[pos - 1]; idx5[pos] = idx5[pos - 1]; pos--;
                }
                val5[pos] = p; idx5[pos] = fi;
            }
        }
    }
#pragma unroll
    for (int q = 0; q < KBM; q++) { tv[tid * KBM + q] = val5[q]; ti[tid * KBM + q] = idx5[q]; }
    __syncthreads();
    // tree merge of sorted 5-lists
    for (int s = 128; s > 0; s >>= 1) {
        if (tid < s) {
            float av[KBM], bv[KBM], ov[KBM];
            int   ai[KBM], bi2[KBM], oi[KBM];
#pragma unroll
            for (int q = 0; q < KBM; q++) {
                av[q] = tv[tid * KBM + q];        ai[q] = ti[tid * KBM + q];
                bv[q] = tv[(tid + s) * KBM + q];  bi2[q] = ti[(tid + s) * KBM + q];
            }
            int ia = 0, ib = 0;
#pragma unroll
            for (int q = 0; q < KBM; q++) {
                bool takeA = (av[ia] > bv[ib]) || (av[ia] == bv[ib] && ai[ia] < bi2[ib]);
                if (takeA) { ov[q] = av[ia]; oi[q] = ai[ia]; ia++; }
                else       { ov[q] = bv[ib]; oi[q] = bi2[ib]; ib++; }
            }
#pragma unroll
            for (int q = 0; q < KBM; q++) { tv[tid * KBM + q] = ov[q]; ti[tid * KBM + q] = oi[q]; }
        }
        __syncthreads();
    }
    if (tid == 0) {
#pragma unroll
        for (int i = 0; i < KBM; i++) {
            int fi = ti[i];
            int beam = fi / V;
            int tok = fi - beam * V;
            s_beam[i] = beam;
            P_t[i * BB + b] = beam;
            x_cur[i * BB + b] = tok;
        }
    }
    __syncthreads();
    // phase C: gather h rows by parent beam
#pragma unroll
    for (int i = 0; i < KBM; i++) {
        int src = (s_beam[i] * BB + b) * H;
        int dst = (i * BB + b) * H;
        for (int c = tid; c < H; c += 256) h_cur[dst + c] = h_next[src + c];
    }
}

// ---------------- final: best beam + ancestry chain ------------------------
__global__ __launch_bounds__(256) void k6a(const float* __restrict__ preds_last,
                                           const int* __restrict__ P,
                                           int* __restrict__ anc) {
    int b = blockIdx.x;
    int tid = threadIdx.x;
    float best = -1.f;
    int bi = 0x7fffffff;
    for (int v = tid; v < V; v += 256)
#pragma unroll
        for (int kk = 0; kk < KBM; kk++) {
            float p = preds_last[(kk * BB + b) * V + v];
            int fi = kk * V + v;
            if (p > best || (p == best && fi < bi)) { best = p; bi = fi; }
        }
    __shared__ float rv[256];
    __shared__ int   ri[256];
    rv[tid] = best; ri[tid] = bi;
    __syncthreads();
    for (int s = 128; s > 0; s >>= 1) {
        if (tid < s) {
            if (rv[tid + s] > rv[tid] || (rv[tid + s] == rv[tid] && ri[tid + s] < ri[tid])) {
                rv[tid] = rv[tid + s]; ri[tid] = ri[tid + s];
            }
        }
        __syncthreads();
    }
    if (tid == 0) {
        int a = ri[0] / V;                     // best_beam
        for (int t = T - 1; t >= 0; t--) {
            a = P[t * R + a * BB + b];
            anc[t * BB + b] = a;
        }
    }
}

__global__ __launch_bounds__(256) void k6b(const float* __restrict__ preds,
                                           const int* __restrict__ anc,
                                           float* __restrict__ out) {
    int idx = blockIdx.x * 256 + threadIdx.x;  // T*BB*V = 1,536,000
    if (idx >= T * BB * V) return;
    int t = idx / (BB * V);
    int rem = idx - t * (BB * V);
    int b = rem / V;
    int v = rem - b * V;
    int a = anc[t * BB + b];
    out[idx] = preds[(size_t)t * R * V + (a * BB + b) * V + v];
}

extern "C" void kernel_launch(void* const* d_in, const int* in_sizes, int n_in,
                              void* d_out, int out_size, void* d_ws, size_t ws_size,
                              hipStream_t stream) {
    (void)in_sizes; (void)n_in; (void)out_size; (void)ws_size;
    const float* hidden    = (const float*)d_in[0];
    const float* embedding = (const float*)d_in[1];
    const float* w_ih      = (const float*)d_in[2];
    const float* w_hh      = (const float*)d_in[3];
    const float* b_ih      = (const float*)d_in[4];
    const float* b_hh      = (const float*)d_in[5];
    const float* w_out     = (const float*)d_in[6];
    const float* b_out     = (const float*)d_in[7];
    float* out = (float*)d_out;

    float* ws     = (float*)d_ws;
    float* h_cur  = ws;
    float* h_next = h_cur + R * H;
    float* gi_buf = h_next + R * H;
    float* gh_buf = gi_buf + G3 * R;
    float* logits = gh_buf + G3 * R;
    float* preds  = logits + R * V;
    int* x_cur = (int*)(preds + (size_t)T * R * V);
    int* P     = x_cur + R;
    int* anc   = P + T * R;

    k0_init<<<80, 256, 0, stream>>>(hidden, h_cur, x_cur);
    for (int t = 0; t < T; t++) {
        float* preds_t = preds + (size_t)t * R * V;
        k1_gemm<<<960, 128, 0, stream>>>(embedding, w_ih, w_hh, x_cur, h_cur, gi_buf, gh_buf);
        k1b_gate<<<80, 256, 0, stream>>>(gi_buf, gh_buf, b_ih, b_hh, x_cur, h_cur, h_next);
        k2_logits<<<1000, 128, 0, stream>>>(w_out, b_out, h_next, logits);
        k5_select<<<8, 256, 0, stream>>>(logits, preds_t, h_next, h_cur, x_cur, P + t * R);
    }
    k6a<<<8, 256, 0, stream>>>(preds + (size_t)(T - 1) * R * V, P, anc);
    k6b<<<6000, 256, 0, stream>>>(preds, anc, out);
}

// Round 3
// 657.478 us; speedup vs baseline: 6.8640x; 6.8640x over previous
//
#include <hip/hip_runtime.h>

#define V 16000
#define E 256
#define H 512
#define BB 8      // batch = number of greedy rows
#define T 12      // lenseq

// Beam search degenerates to greedy: prob stays all-ones so scores==pred; at
// step 0 all 5 beams are bit-identical, top_k tie-break (value desc, index asc)
// makes every beam pick the same argmax token with parent permutation =
// identity, forever. Final best_beam = 0. So: 8 independent greedy decodes,
// pred_t written directly to out[t].
// R2 bug (fixed here): h buffers must ping-pong; R2 re-read initial hidden
// every step.

// ---------------- init: h_cur = hidden, x = SOS ----------------------------
__global__ __launch_bounds__(256) void k0_init(const float* __restrict__ hidden,
                                               float* __restrict__ h_cur,
                                               int* __restrict__ x_cur) {
    int idx = blockIdx.x * 256 + threadIdx.x;   // BB*H = 4096
    if (idx < BB * H) {
        h_cur[idx] = hidden[idx];
        if (idx < BB) x_cur[idx] = 1;           // SOS
    }
}

// ---------------- GRU dot products: gi = emb@w_ih^T, gh = h@w_hh^T ---------
// grid 96 x 256. blocks [0,48): gh (K=512). blocks [48,96): gi (K=256).
// per block: 32 j x 8 r, one dot per thread.
__global__ __launch_bounds__(256) void kg_gemm(const float* __restrict__ emb_tab,
                                               const float* __restrict__ w_ih,
                                               const float* __restrict__ w_hh,
                                               const int* __restrict__ x_cur,
                                               const float* __restrict__ h_cur,
                                               float* __restrict__ gi_buf,
                                               float* __restrict__ gh_buf) {
    int bid = blockIdx.x;
    bool is_gh = bid < 48;
    int lb = is_gh ? bid : bid - 48;
    int j = lb * 32 + (threadIdx.x >> 3);       // 0..1535
    int r = threadIdx.x & 7;                    // 0..7

    if (is_gh) {
        const float* w = w_hh + j * H;
        const float* hv = h_cur + r * H;
        float a0 = 0.f, a1 = 0.f;
        for (int k = 0; k < H; k += 4) {
            float4 a = *(const float4*)(w + k);
            float4 b = *(const float4*)(hv + k);
            a0 += a.x * b.x + a.y * b.y;
            a1 += a.z * b.z + a.w * b.w;
        }
        gh_buf[j * BB + r] = a0 + a1;
    } else {
        const float* w = w_ih + j * E;
        const float* ev = emb_tab + (size_t)x_cur[r] * E;
        float a0 = 0.f, a1 = 0.f;
        for (int k = 0; k < E; k += 4) {
            float4 a = *(const float4*)(w + k);
            float4 b = *(const float4*)(ev + k);
            a0 += a.x * b.x + a.y * b.y;
            a1 += a.z * b.z + a.w * b.w;
        }
        gi_buf[j * BB + r] = a0 + a1;
    }
}

// ---------------- gates + blend: h_next = done ? h : GRU(h) ----------------
__global__ __launch_bounds__(256) void kg_gate(const float* __restrict__ gi_buf,
                                               const float* __restrict__ gh_buf,
                                               const float* __restrict__ b_ih,
                                               const float* __restrict__ b_hh,
                                               const int* __restrict__ x_cur,
                                               const float* __restrict__ h_cur,
                                               float* __restrict__ h_next) {
    int idx = blockIdx.x * 256 + threadIdx.x;   // BB*H = 4096
    if (idx >= BB * H) return;
    int r = idx >> 9;
    int j = idx & (H - 1);
    int x = x_cur[r];
    bool done = (x == 2) || (x == 0);           // EOS | PAD
    float ir  = gi_buf[j * BB + r]            + b_ih[j];
    float iz  = gi_buf[(H + j) * BB + r]      + b_ih[H + j];
    float inn = gi_buf[(2 * H + j) * BB + r]  + b_ih[2 * H + j];
    float hr  = gh_buf[j * BB + r]            + b_hh[j];
    float hz  = gh_buf[(H + j) * BB + r]      + b_hh[H + j];
    float hn  = gh_buf[(2 * H + j) * BB + r]  + b_hh[2 * H + j];
    float rg = 1.f / (1.f + __expf(-(ir + hr)));
    float zg = 1.f / (1.f + __expf(-(iz + hz)));
    float ng = tanhf(inn + rg * hn);
    float ho = h_cur[idx];
    float hv = (1.f - zg) * ng + zg * ho;
    h_next[idx] = done ? ho : hv;
}

// ---------------- partial logits: K split 4 ways ---------------------------
// grid (63, 4) x 256. thread: one vocab col v, K-quarter kq, all 8 rows.
__global__ __launch_bounds__(256) void klog(const float* __restrict__ w_out,
                                            const float* __restrict__ h,
                                            float* __restrict__ part) {
    int v = blockIdx.x * 256 + threadIdx.x;
    int kq = blockIdx.y;                        // 0..3
    if (v >= V) return;
    const float* w = w_out + (size_t)v * H + kq * 128;
    const float* hb = h + kq * 128;             // uniform base -> scalar loads
    float acc[8] = {0.f, 0.f, 0.f, 0.f, 0.f, 0.f, 0.f, 0.f};
    for (int k = 0; k < 128; k += 4) {
        float4 w4 = *(const float4*)(w + k);
#pragma unroll
        for (int r = 0; r < 8; r++) {
            float4 h4 = *(const float4*)(hb + r * H + k);
            acc[r] += w4.x * h4.x + w4.y * h4.y + w4.z * h4.z + w4.w * h4.w;
        }
    }
#pragma unroll
    for (int r = 0; r < 8; r++) part[(kq * 8 + r) * V + v] = acc[r];
}

// ---- select: softmax (no max-shift), argmax, out write. 1 block/batch -----
__global__ __launch_bounds__(1024) void ksel(const float* __restrict__ part,
                                             const float* __restrict__ b_out,
                                             float* __restrict__ out_t,
                                             int* __restrict__ x_cur) {
    int b = blockIdx.x;
    int tid = threadIdx.x;
    int x = x_cur[b];
    bool done = (x == 0) || (x == 2);

    if (done) {
        for (int v = tid; v < V; v += 1024) out_t[b * V + v] = (v == 0) ? 1.f : 0.f;
        if (tid == 0) x_cur[b] = 0;             // PAD; stays done
        return;
    }

    __shared__ float rs[1024];
    __shared__ float rv[1024];
    __shared__ int   ri[1024];

    float e[16];
    float sum = 0.f;
#pragma unroll
    for (int i = 0; i < 16; i++) {
        int v = tid + i * 1024;
        if (v < V) {
            float l = part[(0 * 8 + b) * V + v] + part[(1 * 8 + b) * V + v]
                    + part[(2 * 8 + b) * V + v] + part[(3 * 8 + b) * V + v]
                    + b_out[v];
            e[i] = __expf(l);
            sum += e[i];
        } else e[i] = -1.f;
    }
    rs[tid] = sum;
    __syncthreads();
    for (int s = 512; s > 0; s >>= 1) {
        if (tid < s) rs[tid] += rs[tid + s];
        __syncthreads();
    }
    float S = rs[0];
    float inv = 1.f / S;

    // probs + argmax (tie-break: value desc, index asc)
    float p[16];
    float best = -1.f;
    int bv = 0x7fffffff;
#pragma unroll
    for (int i = 0; i < 16; i++) {
        int v = tid + i * 1024;
        if (v < V) {
            p[i] = e[i] * inv;
            if (p[i] > best || (p[i] == best && v < bv)) { best = p[i]; bv = v; }
        }
    }
    rv[tid] = best; ri[tid] = bv;
    __syncthreads();
    for (int s = 512; s > 0; s >>= 1) {
        if (tid < s) {
            if (rv[tid + s] > rv[tid] ||
                (rv[tid + s] == rv[tid] && ri[tid + s] < ri[tid])) {
                rv[tid] = rv[tid + s]; ri[tid] = ri[tid + s];
            }
        }
        __syncthreads();
    }
    if (tid == 0) x_cur[b] = ri[0];             // next token = argmax

    // write pred_t for this batch row
#pragma unroll
    for (int i = 0; i < 16; i++) {
        int v = tid + i * 1024;
        if (v < V) out_t[b * V + v] = p[i];
    }
}

extern "C" void kernel_launch(void* const* d_in, const int* in_sizes, int n_in,
                              void* d_out, int out_size, void* d_ws, size_t ws_size,
                              hipStream_t stream) {
    (void)in_sizes; (void)n_in; (void)out_size; (void)ws_size;
    const float* hidden    = (const float*)d_in[0];
    const float* embedding = (const float*)d_in[1];
    const float* w_ih      = (const float*)d_in[2];
    const float* w_hh      = (const float*)d_in[3];
    const float* b_ih      = (const float*)d_in[4];
    const float* b_hh      = (const float*)d_in[5];
    const float* w_out     = (const float*)d_in[6];
    const float* b_out     = (const float*)d_in[7];
    float* out = (float*)d_out;

    float* ws   = (float*)d_ws;
    float* hA   = ws;                            // 4096
    float* hB   = hA + BB * H;                   // 4096
    float* gi_buf = hB + BB * H;                 // 12288
    float* gh_buf = gi_buf + 3 * H * BB;         // 12288
    float* part   = gh_buf + 3 * H * BB;         // 4*8*16000
    int*   x_cur  = (int*)(part + 4 * BB * V);   // 8

    k0_init<<<16, 256, 0, stream>>>(hidden, hA, x_cur);
    for (int t = 0; t < T; t++) {
        float* h_cur  = (t & 1) ? hB : hA;
        float* h_next = (t & 1) ? hA : hB;
        kg_gemm<<<96, 256, 0, stream>>>(embedding, w_ih, w_hh, x_cur, h_cur, gi_buf, gh_buf);
        kg_gate<<<16, 256, 0, stream>>>(gi_buf, gh_buf, b_ih, b_hh, x_cur, h_cur, h_next);
        klog<<<dim3(63, 4), 256, 0, stream>>>(w_out, h_next, part);
        ksel<<<8, 1024, 0, stream>>>(part, b_out, out + (size_t)t * BB * V, x_cur);
    }
}